// Round 1
// baseline (1895.476 us; speedup 1.0000x reference)
//
#include <hip/hip_runtime.h>

// TriangleMultiplicationCpp (OUTGOING), N=512, C=128, fp32 in/out.
// Round 1: correct fp32-compute baseline, bf16 workspace.
// ws layout (bytes): a[0, 64M) b[64M, 128M) g[128M, 192M) t[192M, 256M)
// total 268,435,456 bytes.

#define NN 512
#define CC 128
#define LN_EPS 1e-5f

__device__ __forceinline__ float bitf(unsigned int u) {
    return __builtin_bit_cast(float, u);
}
__device__ __forceinline__ float b2f(unsigned short u) {
    return bitf(((unsigned int)u) << 16);
}
__device__ __forceinline__ unsigned short f2b(float f) {
    unsigned int u = __builtin_bit_cast(unsigned int, f);
    u = u + 0x7FFFu + ((u >> 16) & 1u);   // RTNE
    return (unsigned short)(u >> 16);
}
__device__ __forceinline__ float sigmoidf(float x) {
    return 1.0f / (1.0f + __expf(-x));
}
__device__ __forceinline__ void unpack8(uint4 u, float* dst) {
    dst[0] = bitf(u.x << 16); dst[1] = bitf(u.x & 0xFFFF0000u);
    dst[2] = bitf(u.y << 16); dst[3] = bitf(u.y & 0xFFFF0000u);
    dst[4] = bitf(u.z << 16); dst[5] = bitf(u.z & 0xFFFF0000u);
    dst[6] = bitf(u.w << 16); dst[7] = bitf(u.w & 0xFFFF0000u);
}

// ---------------------------------------------------------------------------
// Kernel 1: LN(act) -> proj/gate/glin projections, fused mask*sigmoid.
// 64 positions per block, 256 threads.
// Chunks: 0..7 -> 64 rows = 32 d-indices interleaved (proj,gate) pairs
//         8..9 -> 64 rows of W_glin
// ---------------------------------------------------------------------------
__global__ __launch_bounds__(256) void k_ln_proj(
    const float* __restrict__ act, const float* __restrict__ mask,
    const float* __restrict__ lw, const float* __restrict__ lb,
    const float* __restrict__ Wproj, const float* __restrict__ Wgate,
    const float* __restrict__ Wglin,
    unsigned short* __restrict__ a_ws, unsigned short* __restrict__ b_ws,
    unsigned short* __restrict__ g_ws)
{
    __shared__ float X[64 * 132];            // 33792 B, rows 16B-aligned
    __shared__ unsigned short W[64 * 132];   // 16896 B, bf16 rows

    const int tid = threadIdx.x;
    const int m0 = blockIdx.x * 64;

    // --- stage act tile (64 x 128 fp32) ---
    const float4* src = (const float4*)(act + (size_t)m0 * CC);
    for (int idx = tid; idx < 64 * 32; idx += 256) {
        int p = idx >> 5, c4 = idx & 31;
        float4 v = src[p * 32 + c4];
        *(float4*)&X[p * 132 + c4 * 4] = v;
    }
    __syncthreads();

    // --- layernorm: 4 threads per position ---
    {
        int p = tid >> 2, q = tid & 3;
        float s = 0.f, ss = 0.f;
        #pragma unroll
        for (int t = 0; t < 32; ++t) {
            float v = X[p * 132 + q * 32 + t];
            s += v; ss += v * v;
        }
        s += __shfl_xor(s, 1); ss += __shfl_xor(ss, 1);
        s += __shfl_xor(s, 2); ss += __shfl_xor(ss, 2);
        float mean = s * (1.0f / 128.0f);
        float var  = ss * (1.0f / 128.0f) - mean * mean;
        float rstd = rsqrtf(var + LN_EPS);
        #pragma unroll
        for (int t = 0; t < 32; ++t) {
            int c = q * 32 + t;
            float v = X[p * 132 + c];
            X[p * 132 + c] = (v - mean) * rstd * lw[c] + lb[c];
        }
    }

    const int tx = tid & 15, ty = tid >> 4;

    for (int chunk = 0; chunk < 10; ++chunk) {
        __syncthreads();
        // --- stage 64 W rows as bf16 ---
        for (int idx = tid; idx < 64 * 32; idx += 256) {
            int r = idx >> 5, k4 = idx & 31;
            const float* wrow;
            if (chunk < 8) {
                int d = chunk * 32 + (r >> 1);
                wrow = (r & 1) ? (Wgate + d * CC) : (Wproj + d * CC);
            } else {
                int d = (chunk - 8) * 64 + r;
                wrow = Wglin + d * CC;
            }
            float4 v = *(const float4*)(wrow + k4 * 4);
            unsigned short* dst = &W[r * 132 + k4 * 4];
            dst[0] = f2b(v.x); dst[1] = f2b(v.y);
            dst[2] = f2b(v.z); dst[3] = f2b(v.w);
        }
        __syncthreads();

        // --- 64x64 GEMM tile: thread = 4 positions x 4 rows ---
        float acc[4][4] = {};
        for (int k = 0; k < 128; k += 4) {
            float4 xr[4];
            #pragma unroll
            for (int pp = 0; pp < 4; ++pp)
                xr[pp] = *(const float4*)&X[(ty * 4 + pp) * 132 + k];
            #pragma unroll
            for (int dd = 0; dd < 4; ++dd) {
                const unsigned short* wp = &W[(tx * 4 + dd) * 132 + k];
                float w0 = b2f(wp[0]), w1 = b2f(wp[1]);
                float w2 = b2f(wp[2]), w3 = b2f(wp[3]);
                #pragma unroll
                for (int pp = 0; pp < 4; ++pp)
                    acc[pp][dd] += xr[pp].x * w0 + xr[pp].y * w1 +
                                   xr[pp].z * w2 + xr[pp].w * w3;
            }
        }

        // --- epilogue ---
        if (chunk < 8) {
            #pragma unroll
            for (int pp = 0; pp < 4; ++pp) {
                int m = m0 + ty * 4 + pp;
                float mk = mask[m];
                int d0 = chunk * 32 + tx * 2;          // global proj index
                float av0 = acc[pp][0] * mk * sigmoidf(acc[pp][1]);
                float av1 = acc[pp][2] * mk * sigmoidf(acc[pp][3]);
                if (d0 < 128) {
                    a_ws[m * CC + d0]     = f2b(av0);
                    a_ws[m * CC + d0 + 1] = f2b(av1);
                } else {
                    b_ws[m * CC + d0 - 128] = f2b(av0);
                    b_ws[m * CC + d0 - 127] = f2b(av1);
                }
            }
        } else {
            #pragma unroll
            for (int pp = 0; pp < 4; ++pp) {
                int m = m0 + ty * 4 + pp;
                int d0 = (chunk - 8) * 64 + tx * 4;
                #pragma unroll
                for (int dd = 0; dd < 4; ++dd)
                    g_ws[m * CC + d0 + dd] = f2b(sigmoidf(acc[pp][dd]));
            }
        }
    }
}

// ---------------------------------------------------------------------------
// Kernel 2: t[i,j,c] = sum_k a[i,k,c] * b[j,k,c]
// Block tile: 32 i x 32 j x 16 c; K staged 8 at a time in fp32 LDS.
// Thread: one channel, 8x8 (i,j) outer product.
// ---------------------------------------------------------------------------
__global__ __launch_bounds__(256) void k_tri(
    const unsigned short* __restrict__ a_ws,
    const unsigned short* __restrict__ b_ws,
    unsigned short* __restrict__ t_ws)
{
    __shared__ float At[32 * 130];   // [i][kk*16 + c], row stride 130
    __shared__ float Bt[32 * 130];

    const int tid = threadIdx.x;
    const int ci = tid & 15;
    const int ig = (tid >> 4) & 3;
    const int jg = tid >> 6;
    const int i0 = blockIdx.x * 32, j0 = blockIdx.y * 32, c0 = blockIdx.z * 16;

    float acc[8][8] = {};

    for (int k0 = 0; k0 < NN; k0 += 8) {
        __syncthreads();
        {   // stage: thread tid loads row (il, kk) of both tiles (16 bf16 each)
            int il = tid >> 3, kk = tid & 7;
            const unsigned short* pa =
                a_ws + (size_t)(i0 + il) * (NN * CC) + (k0 + kk) * CC + c0;
            const unsigned short* pb =
                b_ws + (size_t)(j0 + il) * (NN * CC) + (k0 + kk) * CC + c0;
            uint4 ua0 = *(const uint4*)pa;
            uint4 ua1 = *(const uint4*)(pa + 8);
            uint4 ub0 = *(const uint4*)pb;
            uint4 ub1 = *(const uint4*)(pb + 8);
            float fa[16], fb[16];
            unpack8(ua0, fa); unpack8(ua1, fa + 8);
            unpack8(ub0, fb); unpack8(ub1, fb + 8);
            float2* da = (float2*)&At[il * 130 + kk * 16];
            float2* db = (float2*)&Bt[il * 130 + kk * 16];
            #pragma unroll
            for (int t = 0; t < 8; ++t) {
                da[t] = make_float2(fa[2 * t], fa[2 * t + 1]);
                db[t] = make_float2(fb[2 * t], fb[2 * t + 1]);
            }
        }
        __syncthreads();

        #pragma unroll
        for (int kk = 0; kk < 8; ++kk) {
            float ar[8], br[8];
            #pragma unroll
            for (int ii = 0; ii < 8; ++ii)
                ar[ii] = At[(ig * 8 + ii) * 130 + kk * 16 + ci];
            #pragma unroll
            for (int jj = 0; jj < 8; ++jj)
                br[jj] = Bt[(jg * 8 + jj) * 130 + kk * 16 + ci];
            #pragma unroll
            for (int ii = 0; ii < 8; ++ii)
                #pragma unroll
                for (int jj = 0; jj < 8; ++jj)
                    acc[ii][jj] += ar[ii] * br[jj];
        }
    }

    // write t (bf16)
    #pragma unroll
    for (int ii = 0; ii < 8; ++ii) {
        int i = i0 + ig * 8 + ii;
        #pragma unroll
        for (int jj = 0; jj < 8; ++jj) {
            int j = j0 + jg * 8 + jj;
            t_ws[(size_t)(i * NN + j) * CC + c0 + ci] = f2b(acc[ii][jj]);
        }
    }
}

// ---------------------------------------------------------------------------
// Kernel 3: out = (LN_c(t) @ W_out^T) * g
// Same skeleton as kernel 1; 2 chunks of 64 W_out rows.
// ---------------------------------------------------------------------------
__global__ __launch_bounds__(256) void k_ln_out(
    const unsigned short* __restrict__ t_ws,
    const unsigned short* __restrict__ g_ws,
    const float* __restrict__ lw, const float* __restrict__ lb,
    const float* __restrict__ Wout,
    float* __restrict__ out)
{
    __shared__ float X[64 * 132];
    __shared__ unsigned short W[64 * 132];

    const int tid = threadIdx.x;
    const int m0 = blockIdx.x * 64;

    // stage t tile (bf16 -> fp32)
    for (int idx = tid; idx < 64 * 16; idx += 256) {
        int p = idx >> 4, g8 = idx & 15;
        uint4 u = *(const uint4*)(t_ws + (size_t)(m0 + p) * CC + g8 * 8);
        float f[8];
        unpack8(u, f);
        float* dst = &X[p * 132 + g8 * 8];
        #pragma unroll
        for (int t = 0; t < 8; ++t) dst[t] = f[t];
    }
    __syncthreads();

    // layernorm over c
    {
        int p = tid >> 2, q = tid & 3;
        float s = 0.f, ss = 0.f;
        #pragma unroll
        for (int t = 0; t < 32; ++t) {
            float v = X[p * 132 + q * 32 + t];
            s += v; ss += v * v;
        }
        s += __shfl_xor(s, 1); ss += __shfl_xor(ss, 1);
        s += __shfl_xor(s, 2); ss += __shfl_xor(ss, 2);
        float mean = s * (1.0f / 128.0f);
        float var  = ss * (1.0f / 128.0f) - mean * mean;
        float rstd = rsqrtf(var + LN_EPS);
        #pragma unroll
        for (int t = 0; t < 32; ++t) {
            int c = q * 32 + t;
            float v = X[p * 132 + c];
            X[p * 132 + c] = (v - mean) * rstd * lw[c] + lb[c];
        }
    }

    const int tx = tid & 15, ty = tid >> 4;

    for (int chunk = 0; chunk < 2; ++chunk) {
        __syncthreads();
        for (int idx = tid; idx < 64 * 32; idx += 256) {
            int r = idx >> 5, k4 = idx & 31;
            const float* wrow = Wout + (chunk * 64 + r) * CC;
            float4 v = *(const float4*)(wrow + k4 * 4);
            unsigned short* dst = &W[r * 132 + k4 * 4];
            dst[0] = f2b(v.x); dst[1] = f2b(v.y);
            dst[2] = f2b(v.z); dst[3] = f2b(v.w);
        }
        __syncthreads();

        float acc[4][4] = {};
        for (int k = 0; k < 128; k += 4) {
            float4 xr[4];
            #pragma unroll
            for (int pp = 0; pp < 4; ++pp)
                xr[pp] = *(const float4*)&X[(ty * 4 + pp) * 132 + k];
            #pragma unroll
            for (int dd = 0; dd < 4; ++dd) {
                const unsigned short* wp = &W[(tx * 4 + dd) * 132 + k];
                float w0 = b2f(wp[0]), w1 = b2f(wp[1]);
                float w2 = b2f(wp[2]), w3 = b2f(wp[3]);
                #pragma unroll
                for (int pp = 0; pp < 4; ++pp)
                    acc[pp][dd] += xr[pp].x * w0 + xr[pp].y * w1 +
                                   xr[pp].z * w2 + xr[pp].w * w3;
            }
        }

        #pragma unroll
        for (int pp = 0; pp < 4; ++pp) {
            int m = m0 + ty * 4 + pp;
            int d0 = chunk * 64 + tx * 4;
            const unsigned short* gp = g_ws + (size_t)m * CC + d0;
            float4 o;
            o.x = acc[pp][0] * b2f(gp[0]);
            o.y = acc[pp][1] * b2f(gp[1]);
            o.z = acc[pp][2] * b2f(gp[2]);
            o.w = acc[pp][3] * b2f(gp[3]);
            *(float4*)(out + (size_t)m * CC + d0) = o;
        }
    }
}

// ---------------------------------------------------------------------------
extern "C" void kernel_launch(void* const* d_in, const int* in_sizes, int n_in,
                              void* d_out, int out_size, void* d_ws, size_t ws_size,
                              hipStream_t stream) {
    const float* act   = (const float*)d_in[0];
    const float* mask  = (const float*)d_in[1];
    const float* lnw   = (const float*)d_in[2];
    const float* lnb   = (const float*)d_in[3];
    const float* Wproj = (const float*)d_in[4];
    const float* Wgate = (const float*)d_in[5];
    const float* lncw  = (const float*)d_in[6];
    const float* lncb  = (const float*)d_in[7];
    const float* Wout  = (const float*)d_in[8];
    const float* Wglin = (const float*)d_in[9];
    float* out = (float*)d_out;

    char* ws = (char*)d_ws;
    unsigned short* a_ws = (unsigned short*)(ws);
    unsigned short* b_ws = (unsigned short*)(ws + 67108864);
    unsigned short* g_ws = (unsigned short*)(ws + 134217728);
    unsigned short* t_ws = (unsigned short*)(ws + 201326592);

    k_ln_proj<<<dim3(4096), dim3(256), 0, stream>>>(
        act, mask, lnw, lnb, Wproj, Wgate, Wglin, a_ws, b_ws, g_ws);

    k_tri<<<dim3(16, 16, 8), dim3(256), 0, stream>>>(a_ws, b_ws, t_ws);

    k_ln_out<<<dim3(4096), dim3(256), 0, stream>>>(
        t_ws, g_ws, lncw, lncb, Wout, out);
}